// Round 14
// baseline (4580.605 us; speedup 1.0000x reference)
//
#include <hip/hip_runtime.h>

#define BATCH 64
#define TSEQ  4096
#define MROWS (BATCH * TSEQ)   // 262144
#define HD    256
#define G3    768

typedef unsigned short u16;
typedef unsigned int   u32;
typedef __attribute__((ext_vector_type(8))) short bf16x8;
typedef __attribute__((ext_vector_type(4))) float f32x4;

__device__ __forceinline__ float bf2f(u16 x) {
  union { u32 u; float f; } v; v.u = ((u32)x) << 16; return v.f;
}
__device__ __forceinline__ u16 f2bf(float x) {
  union { float f; u32 u; } v; v.f = x;
  u32 r = (v.u + 0x7fffu + ((v.u >> 16) & 1u)) >> 16;
  return (u16)r;
}
__device__ __forceinline__ float fsig(float x) {
  float e = __expf(-x);
  return __builtin_amdgcn_rcpf(1.0f + e);
}
__device__ __forceinline__ float ftanh(float x) {
  float e = __expf(-2.0f * x);
  return 2.0f * __builtin_amdgcn_rcpf(1.0f + e) - 1.0f;
}

#define M_NSEG 0
#define M_CNT 8
#define M_CUR 80

// bf16 h LDS addressing: row-major [64][256] with 16B-chunk XOR swizzle.
// Conflict-free for both the A-frag b128 reads (8-lane phases span all banks)
// and the scattered b16 update writes.
#define HB(row, col) (((row) << 8) + ((((col) >> 3) ^ ((row) & 7)) << 3) + ((col) & 7))

// ---- prep2: LDS-tiled coalesced transpose f32 -> bf16 [N][K]; block 0 zeros meta ----
__global__ __launch_bounds__(256) void k_prep2(const float* __restrict__ Wx,
    const float* __restrict__ Wh, const float* __restrict__ Wo,
    u16* __restrict__ WxT, u16* __restrict__ WhT, u16* __restrict__ WoT,
    int* __restrict__ meta) {
  __shared__ float t[64][65];
  int bid = blockIdx.x;
  if (bid == 0) meta[threadIdx.x] = 0;
  const float* src; u16* dst; int W; int tile;
  if (bid < 48)      { src = Wx; dst = WxT; W = G3; tile = bid; }
  else if (bid < 96) { src = Wh; dst = WhT; W = G3; tile = bid - 48; }
  else               { src = Wo; dst = WoT; W = HD; tile = bid - 96; }
  int ntn = W / 64;
  int kb = (tile / ntn) * 64, nb = (tile % ntn) * 64;
  int r = threadIdx.x >> 6, c = threadIdx.x & 63;
  #pragma unroll
  for (int p = 0; p < 16; p++)
    t[p * 4 + r][c] = src[(size_t)(kb + p * 4 + r) * W + nb + c];
  __syncthreads();
  #pragma unroll
  for (int p = 0; p < 16; p++)
    dst[(size_t)(nb + p * 4 + r) * HD + kb + c] = f2bf(t[c][p * 4 + r]);
}

// ---- conv: b_batch f32 -> bf16 ----
__global__ __launch_bounds__(256) void k_conv(const float* __restrict__ src,
                                              u16* __restrict__ dst) {
  size_t i = (size_t)blockIdx.x * 256 + threadIdx.x;
  size_t stride = (size_t)gridDim.x * 256;
  const size_t n8 = (size_t)MROWS * HD / 8;
  for (; i < n8; i += stride) {
    float4 a = ((const float4*)src)[2 * i];
    float4 b = ((const float4*)src)[2 * i + 1];
    ushort4 lo, hi;
    lo.x = f2bf(a.x); lo.y = f2bf(a.y); lo.z = f2bf(a.z); lo.w = f2bf(a.w);
    hi.x = f2bf(b.x); hi.y = f2bf(b.y); hi.z = f2bf(b.z); hi.w = f2bf(b.w);
    ((ushort4*)dst)[2 * i] = lo;
    ((ushort4*)dst)[2 * i + 1] = hi;
  }
}

// ---- segment discovery + histogram (validated) ----
__global__ __launch_bounds__(256) void k_find(const float* __restrict__ is_summ,
    u32* __restrict__ tmp, int* __restrict__ meta) {
  int idx = blockIdx.x * 256 + threadIdx.x;
  if (idx >= MROWS) return;
  int b = idx >> 12, t = idx & 4095;
  bool start = (t == 0) || (is_summ[idx - 1] != 0.0f);
  if (!start) return;
  int tt = t;
  while (tt < 4095 && is_summ[(b << 12) + tt] == 0.0f) tt++;
  int L = tt - t + 1;
  int slot = atomicAdd(&meta[M_NSEG], 1);
  tmp[slot] = (u32)idx | ((u32)L << 18);
  int bk = L < 64 ? L : 64;
  atomicAdd(&meta[M_CNT + bk], 1);
}

__global__ void k_buckets(int* __restrict__ meta) {
  if (threadIdx.x != 0) return;
  int acc = 0;
  for (int L = 64; L >= 1; --L) {
    meta[M_CUR + L] = acc;
    acc += meta[M_CNT + L];
  }
}

__global__ __launch_bounds__(256) void k_scatter(const u32* __restrict__ tmp,
    u32* __restrict__ sorted, int* __restrict__ meta) {
  int n = meta[M_NSEG];
  int stride = gridDim.x * 256;
  for (int i = blockIdx.x * 256 + threadIdx.x; i < n; i += stride) {
    u32 rec = tmp[i];
    int L = (int)(rec >> 18);
    int bk = L < 64 ? L : 64;
    int slot = atomicAdd(&meta[M_CUR + bk], 1);
    sorted[slot] = rec;
  }
}

// ---- MFMA GEMM (validated R10-R13): 128x64 tile, XCD swizzle, bf16 A ----
template<int N>
__global__ __launch_bounds__(256) void k_gemm(const u16* __restrict__ A,
    const u16* __restrict__ BT, const float* __restrict__ bias,
    u16* __restrict__ C) {
  constexpr int NB = N / 64;
  constexpr int NWG = (MROWS / 128) * NB;
  constexpr int CPX = NWG / 8;
  int bid = blockIdx.x;
  int wg = (bid & 7) * CPX + (bid >> 3);
  int mb = wg / NB, nb = wg % NB;
  int wv = threadIdx.x >> 6, lane = threadIdx.x & 63;
  int lr = lane & 15, lk = (lane >> 4) * 8;
  int m0 = mb * 128 + wv * 32;
  int n0 = nb * 64;
  f32x4 acc[2][4] = {};
  #pragma unroll
  for (int kk = 0; kk < 8; kk++) {
    bf16x8 a0 = *(const bf16x8*)(A + (size_t)(m0 + lr) * HD + kk * 32 + lk);
    bf16x8 a1 = *(const bf16x8*)(A + (size_t)(m0 + 16 + lr) * HD + kk * 32 + lk);
    #pragma unroll
    for (int ns = 0; ns < 4; ns++) {
      bf16x8 bv = *(const bf16x8*)(BT + (size_t)(n0 + ns * 16 + lr) * HD + kk * 32 + lk);
      acc[0][ns] = __builtin_amdgcn_mfma_f32_16x16x32_bf16(a0, bv, acc[0][ns], 0, 0, 0);
      acc[1][ns] = __builtin_amdgcn_mfma_f32_16x16x32_bf16(a1, bv, acc[1][ns], 0, 0, 0);
    }
  }
  #pragma unroll
  for (int mi = 0; mi < 2; mi++) {
    int r0 = m0 + mi * 16 + (lane >> 4) * 4;
    #pragma unroll
    for (int ns = 0; ns < 4; ns++) {
      int col = n0 + ns * 16 + lr;
      float bv = bias[col];
      #pragma unroll
      for (int i = 0; i < 4; i++)
        C[(size_t)(r0 + i) * N + col] = f2bf(acc[mi][ns][i] + bv);
    }
  }
}

// ---- scan6: 1 wave/block, 64 segments (4 MFMA A-groups), zero barriers. ----
// h carried bf16 in LDS [64][256] (HB swizzle, 32 KB -> 5 blocks/CU). Each
// Wh/Wo B-fragment load feeds 4 MFMAs. af register-cached per step (scan5's
// validated in-place-update ordering).
__global__ __launch_bounds__(64) void k_scan6(const u16* __restrict__ gx,
    const u16* __restrict__ WhT, const u16* __restrict__ WoT,
    const float* __restrict__ bh, const float* __restrict__ bo,
    const float* __restrict__ is_summ, float* __restrict__ out,
    float* __restrict__ h_last, const u32* __restrict__ sorted,
    const int* __restrict__ meta) {
  __shared__ u16 h[64 * 256];    // 32 KB bf16
  int nseg = meta[M_NSEG];
  int lane = threadIdx.x;
  int lr = lane & 15, g2 = lane >> 4;
  int sbase = blockIdx.x * 64;
  if (sbase >= nseg) return;

  int gsv[16], Lv[16];   // gi = g*4 + i -> segment sbase + g*16 + g2*4 + i
  #pragma unroll
  for (int g = 0; g < 4; g++)
    #pragma unroll
    for (int i = 0; i < 4; i++) {
      int s = sbase + g * 16 + g2 * 4 + i;
      u32 rec = (s < nseg) ? sorted[s] : 0u;
      gsv[g * 4 + i] = (int)(rec & 0x3FFFFu);
      Lv[g * 4 + i]  = (s < nseg) ? (int)(rec >> 18) : 0;
    }
  int lm = 0;
  #pragma unroll
  for (int gi = 0; gi < 16; gi++) lm = max(lm, Lv[gi]);
  #pragma unroll
  for (int off = 32; off; off >>= 1) lm = max(lm, __shfl_xor(lm, off));

  bf16x8 af[4][8];   // A-frags of h_k, built once per step (static idx only)

  for (int k = 0; k < lm; k++) {
    if (k == 0) {
      // ---- k=0: h_prev = 0, gh = bh; also zeros dead rows ----
      for (int w = 0; w < 16; w++) {
        int col = w * 16 + lr;
        float bhr = bh[col], bhz = bh[col + 256], bhn = bh[col + 512];
        #pragma unroll
        for (int g = 0; g < 4; g++)
          #pragma unroll
          for (int i = 0; i < 4; i++) {
            int gi = g * 4 + i;
            int row = g * 16 + g2 * 4 + i;
            float hnew = 0.0f;
            if (Lv[gi] > 0) {
              int gidx = gsv[gi];
              const u16* grow = gx + (size_t)gidx * G3 + col;
              float gr = bf2f(grow[0]), gz = bf2f(grow[256]), gn = bf2f(grow[512]);
              float r = fsig(gr + bhr);
              float z = fsig(gz + bhz);
              float nn = ftanh(gn + r * bhn);
              hnew = (1.0f - z) * nn;
              if (((gidx + 1) & 4095) == 0) {
                float m = 1.0f - is_summ[gidx];
                h_last[(size_t)(gidx >> 12) * HD + col] = m * hnew;
              }
            }
            h[HB(row, col)] = f2bf(hnew);
          }
      }
    } else {
      // ---- phase A: gh = h_{k-1} @ Wh (af cached) + gate update in place ----
      for (int w = 0; w < 16; w++) {
        f32x4 ar[4] = {}, az[4] = {}, an[4] = {};
        const u16* wr = WhT + (size_t)(w * 16 + lr) * HD + g2 * 8;
        #pragma unroll
        for (int kk = 0; kk < 8; kk++) {
          bf16x8 b0 = *(const bf16x8*)(wr + kk * 32);
          bf16x8 b1 = *(const bf16x8*)(wr + (size_t)256 * HD + kk * 32);
          bf16x8 b2 = *(const bf16x8*)(wr + (size_t)512 * HD + kk * 32);
          #pragma unroll
          for (int g = 0; g < 4; g++) {
            ar[g] = __builtin_amdgcn_mfma_f32_16x16x32_bf16(af[g][kk], b0, ar[g], 0, 0, 0);
            az[g] = __builtin_amdgcn_mfma_f32_16x16x32_bf16(af[g][kk], b1, az[g], 0, 0, 0);
            an[g] = __builtin_amdgcn_mfma_f32_16x16x32_bf16(af[g][kk], b2, an[g], 0, 0, 0);
          }
        }
        int col = w * 16 + lr;
        float bhr = bh[col], bhz = bh[col + 256], bhn = bh[col + 512];
        #pragma unroll
        for (int g = 0; g < 4; g++)
          #pragma unroll
          for (int i = 0; i < 4; i++) {
            int gi = g * 4 + i;
            if (k < Lv[gi]) {
              int gidx = gsv[gi] + k;
              const u16* grow = gx + (size_t)gidx * G3 + col;
              float gr = bf2f(grow[0]), gz = bf2f(grow[256]), gn = bf2f(grow[512]);
              int row = g * 16 + g2 * 4 + i;
              float hp = bf2f(h[HB(row, col)]);
              float r = fsig(gr + ar[g][i] + bhr);
              float z = fsig(gz + az[g][i] + bhz);
              float nn = ftanh(gn + r * (an[g][i] + bhn));
              float hnew = (1.0f - z) * nn + z * hp;
              h[HB(row, col)] = f2bf(hnew);
              if (((gidx + 1) & 4095) == 0) {
                float m = 1.0f - is_summ[gidx];
                h_last[(size_t)(gidx >> 12) * HD + col] = m * hnew;
              }
            }
          }
      }
    }
    // ---- rebuild af from h_k (wave-private LDS; waitcnt, no barrier) ----
    asm volatile("s_waitcnt lgkmcnt(0)" ::: "memory");
    #pragma unroll
    for (int g = 0; g < 4; g++)
      #pragma unroll
      for (int kk = 0; kk < 8; kk++)
        af[g][kk] = *(const bf16x8*)&h[HB(g * 16 + lr, kk * 32 + g2 * 8)];
    // ---- phase B: r_out = h_k @ Wo + bo (WoT from L2, 4 MFMAs per load) ----
    for (int w = 0; w < 16; w++) {
      f32x4 ao[4] = {};
      const u16* wr = WoT + (size_t)(w * 16 + lr) * HD + g2 * 8;
      #pragma unroll
      for (int kk = 0; kk < 8; kk++) {
        bf16x8 bv = *(const bf16x8*)(wr + kk * 32);
        #pragma unroll
        for (int g = 0; g < 4; g++)
          ao[g] = __builtin_amdgcn_mfma_f32_16x16x32_bf16(af[g][kk], bv, ao[g], 0, 0, 0);
      }
      int col = w * 16 + lr;
      float bov = bo[col];
      #pragma unroll
      for (int g = 0; g < 4; g++)
        #pragma unroll
        for (int i = 0; i < 4; i++)
          if (k < Lv[g * 4 + i])
            out[(size_t)(gsv[g * 4 + i] + k) * HD + col] = ao[g][i] + bov;
    }
  }
}

extern "C" void kernel_launch(void* const* d_in, const int* in_sizes, int n_in,
                              void* d_out, int out_size, void* d_ws, size_t ws_size,
                              hipStream_t stream) {
  const int exp_sizes[8] = {BATCH * TSEQ * HD, BATCH * TSEQ, HD * G3, HD * G3,
                            G3, G3, HD * HD, HD};
  if (n_in != 8) return;
  for (int i = 0; i < 8; i++)
    if (in_sizes[i] != exp_sizes[i]) return;

  const float* b_batch = (const float*)d_in[0];
  const float* is_summ = (const float*)d_in[1];
  const float* Wx = (const float*)d_in[2];
  const float* Wh = (const float*)d_in[3];
  const float* bx = (const float*)d_in[4];
  const float* bh = (const float*)d_in[5];
  const float* Wo = (const float*)d_in[6];
  const float* bo = (const float*)d_in[7];

  float* out = (float*)d_out;
  float* h_last = out + (size_t)MROWS * HD;

  char* ws = (char*)d_ws;
  size_t o = 0;
  u16* gx     = (u16*)(ws + o); o += (size_t)MROWS * G3 * 2;   // 402,653,184
  u16* Abf    = (u16*)(ws + o); o += (size_t)MROWS * HD * 2;   // 134,217,728
  u16* WxT    = (u16*)(ws + o); o += (size_t)G3 * HD * 2;
  u16* WhT    = (u16*)(ws + o); o += (size_t)G3 * HD * 2;
  u16* WoT    = (u16*)(ws + o); o += (size_t)HD * HD * 2;
  int* meta   = (int*)(ws + o); o += 1024;
  u32* tmp    = (u32*)(ws + o); o += (size_t)MROWS * 4;
  u32* sorted = (u32*)(ws + o); o += (size_t)MROWS * 4;
  if (ws_size < o) return;

  k_prep2<<<112, 256, 0, stream>>>(Wx, Wh, Wo, WxT, WhT, WoT, meta);
  k_conv<<<2048, 256, 0, stream>>>(b_batch, Abf);
  k_find<<<MROWS / 256, 256, 0, stream>>>(is_summ, tmp, meta);
  k_buckets<<<1, 64, 0, stream>>>(meta);
  k_scatter<<<256, 256, 0, stream>>>(tmp, sorted, meta);
  k_gemm<G3><<<(MROWS / 128) * (G3 / 64), 256, 0, stream>>>(Abf, WxT, bx, gx);
  k_scan6<<<MROWS / 64, 64, 0, stream>>>(gx, WhT, WoT, bh, bo, is_summ,
                                         out, h_last, sorted, meta);
}

// Round 15
// 3287.798 us; speedup vs baseline: 1.3932x; 1.3932x over previous
//
#include <hip/hip_runtime.h>

#define BATCH 64
#define TSEQ  4096
#define MROWS (BATCH * TSEQ)   // 262144
#define HD    256
#define G3    768

typedef unsigned short u16;
typedef unsigned int   u32;
typedef __attribute__((ext_vector_type(8))) short bf16x8;
typedef __attribute__((ext_vector_type(4))) float f32x4;

__device__ __forceinline__ float bf2f(u16 x) {
  union { u32 u; float f; } v; v.u = ((u32)x) << 16; return v.f;
}
__device__ __forceinline__ u16 f2bf(float x) {
  union { float f; u32 u; } v; v.f = x;
  u32 r = (v.u + 0x7fffu + ((v.u >> 16) & 1u)) >> 16;
  return (u16)r;
}
__device__ __forceinline__ float fsig(float x) {
  float e = __expf(-x);
  return __builtin_amdgcn_rcpf(1.0f + e);
}
__device__ __forceinline__ float ftanh(float x) {
  float e = __expf(-2.0f * x);
  return 2.0f * __builtin_amdgcn_rcpf(1.0f + e) - 1.0f;
}
__device__ __forceinline__ bf16x8 pack8(float4 a, float4 b) {
  bf16x8 r;
  r[0] = (short)f2bf(a.x); r[1] = (short)f2bf(a.y);
  r[2] = (short)f2bf(a.z); r[3] = (short)f2bf(a.w);
  r[4] = (short)f2bf(b.x); r[5] = (short)f2bf(b.y);
  r[6] = (short)f2bf(b.z); r[7] = (short)f2bf(b.w);
  return r;
}

#define M_NSEG 0
#define M_CNT 8
#define M_CUR 80

// h LDS col swizzle (validated R10/R13): address computed PER float4.
#define HCOL(r, c) ((c) ^ (((r) & 7) << 2))

// ---- prep2: LDS-tiled coalesced transpose f32 -> bf16 [N][K]; block 0 zeros meta ----
__global__ __launch_bounds__(256) void k_prep2(const float* __restrict__ Wx,
    const float* __restrict__ Wh, const float* __restrict__ Wo,
    u16* __restrict__ WxT, u16* __restrict__ WhT, u16* __restrict__ WoT,
    int* __restrict__ meta) {
  __shared__ float t[64][65];
  int bid = blockIdx.x;
  if (bid == 0) meta[threadIdx.x] = 0;
  const float* src; u16* dst; int W; int tile;
  if (bid < 48)      { src = Wx; dst = WxT; W = G3; tile = bid; }
  else if (bid < 96) { src = Wh; dst = WhT; W = G3; tile = bid - 48; }
  else               { src = Wo; dst = WoT; W = HD; tile = bid - 96; }
  int ntn = W / 64;
  int kb = (tile / ntn) * 64, nb = (tile % ntn) * 64;
  int r = threadIdx.x >> 6, c = threadIdx.x & 63;
  #pragma unroll
  for (int p = 0; p < 16; p++)
    t[p * 4 + r][c] = src[(size_t)(kb + p * 4 + r) * W + nb + c];
  __syncthreads();
  #pragma unroll
  for (int p = 0; p < 16; p++)
    dst[(size_t)(nb + p * 4 + r) * HD + kb + c] = f2bf(t[c][p * 4 + r]);
}

// ---- conv: b_batch f32 -> bf16 ----
__global__ __launch_bounds__(256) void k_conv(const float* __restrict__ src,
                                              u16* __restrict__ dst) {
  size_t i = (size_t)blockIdx.x * 256 + threadIdx.x;
  size_t stride = (size_t)gridDim.x * 256;
  const size_t n8 = (size_t)MROWS * HD / 8;
  for (; i < n8; i += stride) {
    float4 a = ((const float4*)src)[2 * i];
    float4 b = ((const float4*)src)[2 * i + 1];
    ushort4 lo, hi;
    lo.x = f2bf(a.x); lo.y = f2bf(a.y); lo.z = f2bf(a.z); lo.w = f2bf(a.w);
    hi.x = f2bf(b.x); hi.y = f2bf(b.y); hi.z = f2bf(b.z); hi.w = f2bf(b.w);
    ((ushort4*)dst)[2 * i] = lo;
    ((ushort4*)dst)[2 * i + 1] = hi;
  }
}

// ---- segment discovery + histogram (validated) ----
__global__ __launch_bounds__(256) void k_find(const float* __restrict__ is_summ,
    u32* __restrict__ tmp, int* __restrict__ meta) {
  int idx = blockIdx.x * 256 + threadIdx.x;
  if (idx >= MROWS) return;
  int b = idx >> 12, t = idx & 4095;
  bool start = (t == 0) || (is_summ[idx - 1] != 0.0f);
  if (!start) return;
  int tt = t;
  while (tt < 4095 && is_summ[(b << 12) + tt] == 0.0f) tt++;
  int L = tt - t + 1;
  int slot = atomicAdd(&meta[M_NSEG], 1);
  tmp[slot] = (u32)idx | ((u32)L << 18);
  int bk = L < 64 ? L : 64;
  atomicAdd(&meta[M_CNT + bk], 1);
}

__global__ void k_buckets(int* __restrict__ meta) {
  if (threadIdx.x != 0) return;
  int acc = 0;
  for (int L = 64; L >= 1; --L) {
    meta[M_CUR + L] = acc;
    acc += meta[M_CNT + L];
  }
}

__global__ __launch_bounds__(256) void k_scatter(const u32* __restrict__ tmp,
    u32* __restrict__ sorted, int* __restrict__ meta) {
  int n = meta[M_NSEG];
  int stride = gridDim.x * 256;
  for (int i = blockIdx.x * 256 + threadIdx.x; i < n; i += stride) {
    u32 rec = tmp[i];
    int L = (int)(rec >> 18);
    int bk = L < 64 ? L : 64;
    int slot = atomicAdd(&meta[M_CUR + bk], 1);
    sorted[slot] = rec;
  }
}

// ---- MFMA GEMM (validated R10-R14): 128x64 tile, XCD swizzle, bf16 A ----
template<int N>
__global__ __launch_bounds__(256) void k_gemm(const u16* __restrict__ A,
    const u16* __restrict__ BT, const float* __restrict__ bias,
    u16* __restrict__ C) {
  constexpr int NB = N / 64;
  constexpr int NWG = (MROWS / 128) * NB;
  constexpr int CPX = NWG / 8;
  int bid = blockIdx.x;
  int wg = (bid & 7) * CPX + (bid >> 3);
  int mb = wg / NB, nb = wg % NB;
  int wv = threadIdx.x >> 6, lane = threadIdx.x & 63;
  int lr = lane & 15, lk = (lane >> 4) * 8;
  int m0 = mb * 128 + wv * 32;
  int n0 = nb * 64;
  f32x4 acc[2][4] = {};
  #pragma unroll
  for (int kk = 0; kk < 8; kk++) {
    bf16x8 a0 = *(const bf16x8*)(A + (size_t)(m0 + lr) * HD + kk * 32 + lk);
    bf16x8 a1 = *(const bf16x8*)(A + (size_t)(m0 + 16 + lr) * HD + kk * 32 + lk);
    #pragma unroll
    for (int ns = 0; ns < 4; ns++) {
      bf16x8 bv = *(const bf16x8*)(BT + (size_t)(n0 + ns * 16 + lr) * HD + kk * 32 + lk);
      acc[0][ns] = __builtin_amdgcn_mfma_f32_16x16x32_bf16(a0, bv, acc[0][ns], 0, 0, 0);
      acc[1][ns] = __builtin_amdgcn_mfma_f32_16x16x32_bf16(a1, bv, acc[1][ns], 0, 0, 0);
    }
  }
  #pragma unroll
  for (int mi = 0; mi < 2; mi++) {
    int r0 = m0 + mi * 16 + (lane >> 4) * 4;
    #pragma unroll
    for (int ns = 0; ns < 4; ns++) {
      int col = n0 + ns * 16 + lr;
      float bv = bias[col];
      #pragma unroll
      for (int i = 0; i < 4; i++)
        C[(size_t)(r0 + i) * N + col] = f2bf(acc[mi][ns][i] + bv);
    }
  }
}

// ---- scan7: 4 waves/block, 16 shared segments; wave wv owns windows wv*4..+3.
// f32 h in shared LDS (16 KB, HCOL swizzle); Wh/Wo B-frags direct from L2.
// 2 barriers per step. Per-step tail latency = scan5 / 4.
__global__ __launch_bounds__(256) void k_scan7(const u16* __restrict__ gx,
    const u16* __restrict__ WhT, const u16* __restrict__ WoT,
    const float* __restrict__ bh, const float* __restrict__ bo,
    const float* __restrict__ is_summ, float* __restrict__ out,
    float* __restrict__ h_last, const u32* __restrict__ sorted,
    const int* __restrict__ meta) {
  __shared__ float h[16][256];    // 16 KB, shared by all 4 waves
  int nseg = meta[M_NSEG];
  int tid = threadIdx.x;
  int wv = tid >> 6, lane = tid & 63;
  int lr = lane & 15, g2 = lane >> 4, lk = g2 * 8;
  int sbase = blockIdx.x * 16;
  if (sbase >= nseg) return;   // block-uniform

  // identical records in every wave (same per-lane mapping)
  int gsv[4], Lv[4];
  #pragma unroll
  for (int i = 0; i < 4; i++) {
    int s = sbase + g2 * 4 + i;
    u32 rec = (s < nseg) ? sorted[s] : 0u;
    gsv[i] = (int)(rec & 0x3FFFFu);
    Lv[i]  = (s < nseg) ? (int)(rec >> 18) : 0;
  }
  int lm = max(max(Lv[0], Lv[1]), max(Lv[2], Lv[3]));
  #pragma unroll
  for (int off = 32; off; off >>= 1) lm = max(lm, __shfl_xor(lm, off));
  // lm identical across waves -> uniform barrier count

  bf16x8 af[8];

  for (int k = 0; k < lm; k++) {
    if (k == 0) {
      // ---- k=0: h_prev = 0, gh = bh; this wave's 4 windows ----
      #pragma unroll
      for (int ww = 0; ww < 4; ww++) {
        int w = wv * 4 + ww;
        int col = w * 16 + lr;
        float bhr = bh[col], bhz = bh[col + 256], bhn = bh[col + 512];
        #pragma unroll
        for (int i = 0; i < 4; i++) {
          int row = g2 * 4 + i;
          float hnew = 0.0f;
          if (Lv[i] > 0) {
            int gidx = gsv[i];
            const u16* grow = gx + (size_t)gidx * G3 + col;
            float gr = bf2f(grow[0]), gz = bf2f(grow[256]), gn = bf2f(grow[512]);
            float r = fsig(gr + bhr);
            float z = fsig(gz + bhz);
            float nn = ftanh(gn + r * bhn);
            hnew = (1.0f - z) * nn;
            if (((gidx + 1) & 4095) == 0) {
              float m = 1.0f - is_summ[gidx];
              h_last[(size_t)(gidx >> 12) * HD + col] = m * hnew;
            }
          }
          h[row][HCOL(row, col)] = hnew;
        }
      }
    } else {
      // ---- phase A: gh = h_{k-1} @ Wh (af from prev iter); this wave's windows ----
      #pragma unroll
      for (int ww = 0; ww < 4; ww++) {
        int w = wv * 4 + ww;
        f32x4 ar = {0,0,0,0}, az = {0,0,0,0}, an = {0,0,0,0};
        const u16* wr = WhT + (size_t)(w * 16 + lr) * HD + lk;
        #pragma unroll
        for (int kk = 0; kk < 8; kk++) {
          bf16x8 b0 = *(const bf16x8*)(wr + kk * 32);
          bf16x8 b1 = *(const bf16x8*)(wr + (size_t)256 * HD + kk * 32);
          bf16x8 b2 = *(const bf16x8*)(wr + (size_t)512 * HD + kk * 32);
          ar = __builtin_amdgcn_mfma_f32_16x16x32_bf16(af[kk], b0, ar, 0, 0, 0);
          az = __builtin_amdgcn_mfma_f32_16x16x32_bf16(af[kk], b1, az, 0, 0, 0);
          an = __builtin_amdgcn_mfma_f32_16x16x32_bf16(af[kk], b2, an, 0, 0, 0);
        }
        int col = w * 16 + lr;
        float bhr = bh[col], bhz = bh[col + 256], bhn = bh[col + 512];
        #pragma unroll
        for (int i = 0; i < 4; i++) {
          if (k < Lv[i]) {
            int row = g2 * 4 + i;
            int gidx = gsv[i] + k;
            const u16* grow = gx + (size_t)gidx * G3 + col;
            float gr = bf2f(grow[0]), gz = bf2f(grow[256]), gn = bf2f(grow[512]);
            float hp = h[row][HCOL(row, col)];
            float r = fsig(gr + ar[i] + bhr);
            float z = fsig(gz + az[i] + bhz);
            float nn = ftanh(gn + r * (an[i] + bhn));
            float hnew = (1.0f - z) * nn + z * hp;
            h[row][HCOL(row, col)] = hnew;
            if (((gidx + 1) & 4095) == 0) {
              float m = 1.0f - is_summ[gidx];
              h_last[(size_t)(gidx >> 12) * HD + col] = m * hnew;
            }
          }
        }
      }
    }
    __syncthreads();   // h_k complete (all windows, all waves)
    // ---- rebuild af from h_k (every wave reads all cols) ----
    #pragma unroll
    for (int kk = 0; kk < 8; kk++) {
      float4 u0 = *(const float4*)&h[lr][HCOL(lr, kk * 32 + lk)];
      float4 u1 = *(const float4*)&h[lr][HCOL(lr, kk * 32 + lk + 4)];
      af[kk] = pack8(u0, u1);
    }
    __syncthreads();   // af reads done before next step's phase A rewrites h
    // ---- phase B: r_out = h_k @ Wo + bo; this wave's windows ----
    #pragma unroll
    for (int ww = 0; ww < 4; ww++) {
      int w = wv * 4 + ww;
      f32x4 ao = {0,0,0,0};
      const u16* wr = WoT + (size_t)(w * 16 + lr) * HD + lk;
      #pragma unroll
      for (int kk = 0; kk < 8; kk++) {
        bf16x8 bv = *(const bf16x8*)(wr + kk * 32);
        ao = __builtin_amdgcn_mfma_f32_16x16x32_bf16(af[kk], bv, ao, 0, 0, 0);
      }
      int col = w * 16 + lr;
      float bov = bo[col];
      #pragma unroll
      for (int i = 0; i < 4; i++)
        if (k < Lv[i])
          out[(size_t)(gsv[i] + k) * HD + col] = ao[i] + bov;
    }
  }
}

extern "C" void kernel_launch(void* const* d_in, const int* in_sizes, int n_in,
                              void* d_out, int out_size, void* d_ws, size_t ws_size,
                              hipStream_t stream) {
  const int exp_sizes[8] = {BATCH * TSEQ * HD, BATCH * TSEQ, HD * G3, HD * G3,
                            G3, G3, HD * HD, HD};
  if (n_in != 8) return;
  for (int i = 0; i < 8; i++)
    if (in_sizes[i] != exp_sizes[i]) return;

  const float* b_batch = (const float*)d_in[0];
  const float* is_summ = (const float*)d_in[1];
  const float* Wx = (const float*)d_in[2];
  const float* Wh = (const float*)d_in[3];
  const float* bx = (const float*)d_in[4];
  const float* bh = (const float*)d_in[5];
  const float* Wo = (const float*)d_in[6];
  const float* bo = (const float*)d_in[7];

  float* out = (float*)d_out;
  float* h_last = out + (size_t)MROWS * HD;

  char* ws = (char*)d_ws;
  size_t o = 0;
  u16* gx     = (u16*)(ws + o); o += (size_t)MROWS * G3 * 2;   // 402,653,184
  u16* Abf    = (u16*)(ws + o); o += (size_t)MROWS * HD * 2;   // 134,217,728
  u16* WxT    = (u16*)(ws + o); o += (size_t)G3 * HD * 2;
  u16* WhT    = (u16*)(ws + o); o += (size_t)G3 * HD * 2;
  u16* WoT    = (u16*)(ws + o); o += (size_t)HD * HD * 2;
  int* meta   = (int*)(ws + o); o += 1024;
  u32* tmp    = (u32*)(ws + o); o += (size_t)MROWS * 4;
  u32* sorted = (u32*)(ws + o); o += (size_t)MROWS * 4;
  if (ws_size < o) return;

  k_prep2<<<112, 256, 0, stream>>>(Wx, Wh, Wo, WxT, WhT, WoT, meta);
  k_conv<<<2048, 256, 0, stream>>>(b_batch, Abf);
  k_find<<<MROWS / 256, 256, 0, stream>>>(is_summ, tmp, meta);
  k_buckets<<<1, 64, 0, stream>>>(meta);
  k_scatter<<<256, 256, 0, stream>>>(tmp, sorted, meta);
  k_gemm<G3><<<(MROWS / 128) * (G3 / 64), 256, 0, stream>>>(Abf, WxT, bx, gx);
  k_scan7<<<MROWS / 16, 256, 0, stream>>>(gx, WhT, WoT, bh, bo, is_summ,
                                          out, h_last, sorted, meta);
}

// Round 16
// 2173.989 us; speedup vs baseline: 2.1070x; 1.5123x over previous
//
#include <hip/hip_runtime.h>

#define BATCH 64
#define TSEQ  4096
#define MROWS (BATCH * TSEQ)   // 262144
#define HD    256
#define G3    768

typedef unsigned short u16;
typedef unsigned int   u32;
typedef __attribute__((ext_vector_type(8))) short bf16x8;
typedef __attribute__((ext_vector_type(4))) float f32x4;

__device__ __forceinline__ float bf2f(u16 x) {
  union { u32 u; float f; } v; v.u = ((u32)x) << 16; return v.f;
}
__device__ __forceinline__ u16 f2bf(float x) {
  union { float f; u32 u; } v; v.f = x;
  u32 r = (v.u + 0x7fffu + ((v.u >> 16) & 1u)) >> 16;
  return (u16)r;
}
__device__ __forceinline__ float fsig(float x) {
  float e = __expf(-x);
  return __builtin_amdgcn_rcpf(1.0f + e);
}
__device__ __forceinline__ float ftanh(float x) {
  float e = __expf(-2.0f * x);
  return 2.0f * __builtin_amdgcn_rcpf(1.0f + e) - 1.0f;
}
__device__ __forceinline__ bf16x8 pack8(float4 a, float4 b) {
  bf16x8 r;
  r[0] = (short)f2bf(a.x); r[1] = (short)f2bf(a.y);
  r[2] = (short)f2bf(a.z); r[3] = (short)f2bf(a.w);
  r[4] = (short)f2bf(b.x); r[5] = (short)f2bf(b.y);
  r[6] = (short)f2bf(b.z); r[7] = (short)f2bf(b.w);
  return r;
}

#define M_NSEG 0
#define M_CNT 8
#define M_CUR 80

// h LDS col swizzle (validated R10/R13): address computed PER float4.
#define HCOL(r, c) ((c) ^ (((r) & 7) << 2))

// ---- prep2: LDS-tiled coalesced transpose f32 -> bf16 [N][K]; block 0 zeros meta ----
__global__ __launch_bounds__(256) void k_prep2(const float* __restrict__ Wx,
    const float* __restrict__ Wh, const float* __restrict__ Wo,
    u16* __restrict__ WxT, u16* __restrict__ WhT, u16* __restrict__ WoT,
    int* __restrict__ meta) {
  __shared__ float t[64][65];
  int bid = blockIdx.x;
  if (bid == 0) meta[threadIdx.x] = 0;
  const float* src; u16* dst; int W; int tile;
  if (bid < 48)      { src = Wx; dst = WxT; W = G3; tile = bid; }
  else if (bid < 96) { src = Wh; dst = WhT; W = G3; tile = bid - 48; }
  else               { src = Wo; dst = WoT; W = HD; tile = bid - 96; }
  int ntn = W / 64;
  int kb = (tile / ntn) * 64, nb = (tile % ntn) * 64;
  int r = threadIdx.x >> 6, c = threadIdx.x & 63;
  #pragma unroll
  for (int p = 0; p < 16; p++)
    t[p * 4 + r][c] = src[(size_t)(kb + p * 4 + r) * W + nb + c];
  __syncthreads();
  #pragma unroll
  for (int p = 0; p < 16; p++)
    dst[(size_t)(nb + p * 4 + r) * HD + kb + c] = f2bf(t[c][p * 4 + r]);
}

// ---- conv: b_batch f32 -> bf16 ----
__global__ __launch_bounds__(256) void k_conv(const float* __restrict__ src,
                                              u16* __restrict__ dst) {
  size_t i = (size_t)blockIdx.x * 256 + threadIdx.x;
  size_t stride = (size_t)gridDim.x * 256;
  const size_t n8 = (size_t)MROWS * HD / 8;
  for (; i < n8; i += stride) {
    float4 a = ((const float4*)src)[2 * i];
    float4 b = ((const float4*)src)[2 * i + 1];
    ushort4 lo, hi;
    lo.x = f2bf(a.x); lo.y = f2bf(a.y); lo.z = f2bf(a.z); lo.w = f2bf(a.w);
    hi.x = f2bf(b.x); hi.y = f2bf(b.y); hi.z = f2bf(b.z); hi.w = f2bf(b.w);
    ((ushort4*)dst)[2 * i] = lo;
    ((ushort4*)dst)[2 * i + 1] = hi;
  }
}

// ---- k_find: two-level histogram (LDS atomics -> 1 global atomic/bucket/block).
// Same-address global-atomic storm was the suspected phantom cost.
__global__ __launch_bounds__(256) void k_find(const float* __restrict__ is_summ,
    u32* __restrict__ tmp, int* __restrict__ meta) {
  __shared__ int lhist[65];
  __shared__ int lcnt, lbase;
  int tid = threadIdx.x;
  if (tid < 65) lhist[tid] = 0;
  if (tid == 0) lcnt = 0;
  __syncthreads();

  int idx = blockIdx.x * 256 + tid;
  u32 rec = 0; int bk = 0, lofs = 0;
  bool start = false;
  if (idx < MROWS) {
    int b = idx >> 12, t = idx & 4095;
    start = (t == 0) || (is_summ[idx - 1] != 0.0f);
    if (start) {
      int tt = t;
      while (tt < 4095 && is_summ[(b << 12) + tt] == 0.0f) tt++;
      int L = tt - t + 1;
      rec = (u32)idx | ((u32)L << 18);
      bk = L < 64 ? L : 64;
      lofs = atomicAdd(&lcnt, 1);
      atomicAdd(&lhist[bk], 1);
    }
  }
  __syncthreads();
  if (tid == 0) lbase = atomicAdd(&meta[M_NSEG], lcnt);
  if (tid >= 1 && tid <= 64 && lhist[tid] > 0)
    atomicAdd(&meta[M_CNT + tid], lhist[tid]);
  __syncthreads();
  if (start) tmp[lbase + lofs] = rec;
}

__global__ void k_buckets(int* __restrict__ meta) {
  if (threadIdx.x != 0) return;
  int acc = 0;
  for (int L = 64; L >= 1; --L) {
    meta[M_CUR + L] = acc;
    acc += meta[M_CNT + L];
  }
}

// ---- k_scatter: two-level (LDS local offsets + 1 global base-reserve/bucket/block) ----
__global__ __launch_bounds__(256) void k_scatter(const u32* __restrict__ tmp,
    u32* __restrict__ sorted, int* __restrict__ meta) {
  __shared__ int lhist[65];
  __shared__ int lbase[65];
  int tid = threadIdx.x;
  if (tid < 65) lhist[tid] = 0;
  __syncthreads();

  int n = meta[M_NSEG];
  int i = blockIdx.x * 256 + tid;
  u32 rec = 0; int bk = 0, lofs = 0;
  bool has = (i < n);
  if (has) {
    rec = tmp[i];
    int L = (int)(rec >> 18);
    bk = L < 64 ? L : 64;
    lofs = atomicAdd(&lhist[bk], 1);
  }
  __syncthreads();
  if (tid >= 1 && tid <= 64 && lhist[tid] > 0)
    lbase[tid] = atomicAdd(&meta[M_CUR + tid], lhist[tid]);
  __syncthreads();
  if (has) sorted[lbase[bk] + lofs] = rec;
}

// ---- MFMA GEMM (validated R10-R15): 128x64 tile, XCD swizzle, bf16 A ----
template<int N>
__global__ __launch_bounds__(256) void k_gemm(const u16* __restrict__ A,
    const u16* __restrict__ BT, const float* __restrict__ bias,
    u16* __restrict__ C) {
  constexpr int NB = N / 64;
  constexpr int NWG = (MROWS / 128) * NB;
  constexpr int CPX = NWG / 8;
  int bid = blockIdx.x;
  int wg = (bid & 7) * CPX + (bid >> 3);
  int mb = wg / NB, nb = wg % NB;
  int wv = threadIdx.x >> 6, lane = threadIdx.x & 63;
  int lr = lane & 15, lk = (lane >> 4) * 8;
  int m0 = mb * 128 + wv * 32;
  int n0 = nb * 64;
  f32x4 acc[2][4] = {};
  #pragma unroll
  for (int kk = 0; kk < 8; kk++) {
    bf16x8 a0 = *(const bf16x8*)(A + (size_t)(m0 + lr) * HD + kk * 32 + lk);
    bf16x8 a1 = *(const bf16x8*)(A + (size_t)(m0 + 16 + lr) * HD + kk * 32 + lk);
    #pragma unroll
    for (int ns = 0; ns < 4; ns++) {
      bf16x8 bv = *(const bf16x8*)(BT + (size_t)(n0 + ns * 16 + lr) * HD + kk * 32 + lk);
      acc[0][ns] = __builtin_amdgcn_mfma_f32_16x16x32_bf16(a0, bv, acc[0][ns], 0, 0, 0);
      acc[1][ns] = __builtin_amdgcn_mfma_f32_16x16x32_bf16(a1, bv, acc[1][ns], 0, 0, 0);
    }
  }
  #pragma unroll
  for (int mi = 0; mi < 2; mi++) {
    int r0 = m0 + mi * 16 + (lane >> 4) * 4;
    #pragma unroll
    for (int ns = 0; ns < 4; ns++) {
      int col = n0 + ns * 16 + lr;
      float bv = bias[col];
      #pragma unroll
      for (int i = 0; i < 4; i++)
        C[(size_t)(r0 + i) * N + col] = f2bf(acc[mi][ns][i] + bv);
    }
  }
}

// ---- scan7 (validated R15) + VGPR cap: __launch_bounds__(256,2) -> <=128 VGPR ----
__global__ __launch_bounds__(256, 2) void k_scan7(const u16* __restrict__ gx,
    const u16* __restrict__ WhT, const u16* __restrict__ WoT,
    const float* __restrict__ bh, const float* __restrict__ bo,
    const float* __restrict__ is_summ, float* __restrict__ out,
    float* __restrict__ h_last, const u32* __restrict__ sorted,
    const int* __restrict__ meta) {
  __shared__ float h[16][256];    // 16 KB, shared by all 4 waves
  int nseg = meta[M_NSEG];
  int tid = threadIdx.x;
  int wv = tid >> 6, lane = tid & 63;
  int lr = lane & 15, g2 = lane >> 4, lk = g2 * 8;
  int sbase = blockIdx.x * 16;
  if (sbase >= nseg) return;   // block-uniform

  int gsv[4], Lv[4];
  #pragma unroll
  for (int i = 0; i < 4; i++) {
    int s = sbase + g2 * 4 + i;
    u32 rec = (s < nseg) ? sorted[s] : 0u;
    gsv[i] = (int)(rec & 0x3FFFFu);
    Lv[i]  = (s < nseg) ? (int)(rec >> 18) : 0;
  }
  int lm = max(max(Lv[0], Lv[1]), max(Lv[2], Lv[3]));
  #pragma unroll
  for (int off = 32; off; off >>= 1) lm = max(lm, __shfl_xor(lm, off));

  bf16x8 af[8];

  for (int k = 0; k < lm; k++) {
    if (k == 0) {
      #pragma unroll
      for (int ww = 0; ww < 4; ww++) {
        int w = wv * 4 + ww;
        int col = w * 16 + lr;
        float bhr = bh[col], bhz = bh[col + 256], bhn = bh[col + 512];
        #pragma unroll
        for (int i = 0; i < 4; i++) {
          int row = g2 * 4 + i;
          float hnew = 0.0f;
          if (Lv[i] > 0) {
            int gidx = gsv[i];
            const u16* grow = gx + (size_t)gidx * G3 + col;
            float gr = bf2f(grow[0]), gz = bf2f(grow[256]), gn = bf2f(grow[512]);
            float r = fsig(gr + bhr);
            float z = fsig(gz + bhz);
            float nn = ftanh(gn + r * bhn);
            hnew = (1.0f - z) * nn;
            if (((gidx + 1) & 4095) == 0) {
              float m = 1.0f - is_summ[gidx];
              h_last[(size_t)(gidx >> 12) * HD + col] = m * hnew;
            }
          }
          h[row][HCOL(row, col)] = hnew;
        }
      }
    } else {
      #pragma unroll
      for (int ww = 0; ww < 4; ww++) {
        int w = wv * 4 + ww;
        f32x4 ar = {0,0,0,0}, az = {0,0,0,0}, an = {0,0,0,0};
        const u16* wr = WhT + (size_t)(w * 16 + lr) * HD + lk;
        #pragma unroll
        for (int kk = 0; kk < 8; kk++) {
          bf16x8 b0 = *(const bf16x8*)(wr + kk * 32);
          bf16x8 b1 = *(const bf16x8*)(wr + (size_t)256 * HD + kk * 32);
          bf16x8 b2 = *(const bf16x8*)(wr + (size_t)512 * HD + kk * 32);
          ar = __builtin_amdgcn_mfma_f32_16x16x32_bf16(af[kk], b0, ar, 0, 0, 0);
          az = __builtin_amdgcn_mfma_f32_16x16x32_bf16(af[kk], b1, az, 0, 0, 0);
          an = __builtin_amdgcn_mfma_f32_16x16x32_bf16(af[kk], b2, an, 0, 0, 0);
        }
        int col = w * 16 + lr;
        float bhr = bh[col], bhz = bh[col + 256], bhn = bh[col + 512];
        #pragma unroll
        for (int i = 0; i < 4; i++) {
          if (k < Lv[i]) {
            int row = g2 * 4 + i;
            int gidx = gsv[i] + k;
            const u16* grow = gx + (size_t)gidx * G3 + col;
            float gr = bf2f(grow[0]), gz = bf2f(grow[256]), gn = bf2f(grow[512]);
            float hp = h[row][HCOL(row, col)];
            float r = fsig(gr + ar[i] + bhr);
            float z = fsig(gz + az[i] + bhz);
            float nn = ftanh(gn + r * (an[i] + bhn));
            float hnew = (1.0f - z) * nn + z * hp;
            h[row][HCOL(row, col)] = hnew;
            if (((gidx + 1) & 4095) == 0) {
              float m = 1.0f - is_summ[gidx];
              h_last[(size_t)(gidx >> 12) * HD + col] = m * hnew;
            }
          }
        }
      }
    }
    __syncthreads();   // h_k complete
    #pragma unroll
    for (int kk = 0; kk < 8; kk++) {
      float4 u0 = *(const float4*)&h[lr][HCOL(lr, kk * 32 + lk)];
      float4 u1 = *(const float4*)&h[lr][HCOL(lr, kk * 32 + lk + 4)];
      af[kk] = pack8(u0, u1);
    }
    __syncthreads();   // af reads done before next phase A rewrites h
    #pragma unroll
    for (int ww = 0; ww < 4; ww++) {
      int w = wv * 4 + ww;
      f32x4 ao = {0,0,0,0};
      const u16* wr = WoT + (size_t)(w * 16 + lr) * HD + lk;
      #pragma unroll
      for (int kk = 0; kk < 8; kk++) {
        bf16x8 bv = *(const bf16x8*)(wr + kk * 32);
        ao = __builtin_amdgcn_mfma_f32_16x16x32_bf16(af[kk], bv, ao, 0, 0, 0);
      }
      int col = w * 16 + lr;
      float bov = bo[col];
      #pragma unroll
      for (int i = 0; i < 4; i++)
        if (k < Lv[i])
          out[(size_t)(gsv[i] + k) * HD + col] = ao[i] + bov;
    }
  }
}

extern "C" void kernel_launch(void* const* d_in, const int* in_sizes, int n_in,
                              void* d_out, int out_size, void* d_ws, size_t ws_size,
                              hipStream_t stream) {
  const int exp_sizes[8] = {BATCH * TSEQ * HD, BATCH * TSEQ, HD * G3, HD * G3,
                            G3, G3, HD * HD, HD};
  if (n_in != 8) return;
  for (int i = 0; i < 8; i++)
    if (in_sizes[i] != exp_sizes[i]) return;

  const float* b_batch = (const float*)d_in[0];
  const float* is_summ = (const float*)d_in[1];
  const float* Wx = (const float*)d_in[2];
  const float* Wh = (const float*)d_in[3];
  const float* bx = (const float*)d_in[4];
  const float* bh = (const float*)d_in[5];
  const float* Wo = (const float*)d_in[6];
  const float* bo = (const float*)d_in[7];

  float* out = (float*)d_out;
  float* h_last = out + (size_t)MROWS * HD;

  char* ws = (char*)d_ws;
  size_t o = 0;
  u16* gx     = (u16*)(ws + o); o += (size_t)MROWS * G3 * 2;   // 402,653,184
  u16* Abf    = (u16*)(ws + o); o += (size_t)MROWS * HD * 2;   // 134,217,728
  u16* WxT    = (u16*)(ws + o); o += (size_t)G3 * HD * 2;
  u16* WhT    = (u16*)(ws + o); o += (size_t)G3 * HD * 2;
  u16* WoT    = (u16*)(ws + o); o += (size_t)HD * HD * 2;
  int* meta   = (int*)(ws + o); o += 1024;
  u32* tmp    = (u32*)(ws + o); o += (size_t)MROWS * 4;
  u32* sorted = (u32*)(ws + o); o += (size_t)MROWS * 4;
  if (ws_size < o) return;

  k_prep2<<<112, 256, 0, stream>>>(Wx, Wh, Wo, WxT, WhT, WoT, meta);
  k_conv<<<2048, 256, 0, stream>>>(b_batch, Abf);
  k_find<<<MROWS / 256, 256, 0, stream>>>(is_summ, tmp, meta);
  k_buckets<<<1, 64, 0, stream>>>(meta);
  k_scatter<<<MROWS / 256, 256, 0, stream>>>(tmp, sorted, meta);
  k_gemm<G3><<<(MROWS / 128) * (G3 / 64), 256, 0, stream>>>(Abf, WxT, bx, gx);
  k_scan7<<<MROWS / 16, 256, 0, stream>>>(gx, WhT, WoT, bh, bo, is_summ,
                                          out, h_last, sorted, meta);
}

// Round 17
// 1995.664 us; speedup vs baseline: 2.2953x; 1.0894x over previous
//
#include <hip/hip_runtime.h>

#define BATCH 64
#define TSEQ  4096
#define MROWS (BATCH * TSEQ)   // 262144
#define HD    256
#define G3    768

typedef unsigned short u16;
typedef unsigned int   u32;
typedef __attribute__((ext_vector_type(8))) short bf16x8;
typedef __attribute__((ext_vector_type(4))) float f32x4;

__device__ __forceinline__ float bf2f(u16 x) {
  union { u32 u; float f; } v; v.u = ((u32)x) << 16; return v.f;
}
__device__ __forceinline__ u16 f2bf(float x) {
  union { float f; u32 u; } v; v.f = x;
  u32 r = (v.u + 0x7fffu + ((v.u >> 16) & 1u)) >> 16;
  return (u16)r;
}
__device__ __forceinline__ float fsig(float x) {
  float e = __expf(-x);
  return __builtin_amdgcn_rcpf(1.0f + e);
}
__device__ __forceinline__ float ftanh(float x) {
  float e = __expf(-2.0f * x);
  return 2.0f * __builtin_amdgcn_rcpf(1.0f + e) - 1.0f;
}

#define M_NSEG 0
#define M_CNT 8
#define M_CUR 80

// bf16 h LDS addressing (validated in scan6/R14): 16B-chunk XOR swizzle.
#define HB(row, col) (((row) << 8) + ((((col) >> 3) ^ ((row) & 7)) << 3) + ((col) & 7))

// ---- prep2: LDS-tiled coalesced transpose f32 -> bf16 [N][K]; block 0 zeros meta ----
__global__ __launch_bounds__(256) void k_prep2(const float* __restrict__ Wx,
    const float* __restrict__ Wh, const float* __restrict__ Wo,
    u16* __restrict__ WxT, u16* __restrict__ WhT, u16* __restrict__ WoT,
    int* __restrict__ meta) {
  __shared__ float t[64][65];
  int bid = blockIdx.x;
  if (bid == 0) meta[threadIdx.x] = 0;
  const float* src; u16* dst; int W; int tile;
  if (bid < 48)      { src = Wx; dst = WxT; W = G3; tile = bid; }
  else if (bid < 96) { src = Wh; dst = WhT; W = G3; tile = bid - 48; }
  else               { src = Wo; dst = WoT; W = HD; tile = bid - 96; }
  int ntn = W / 64;
  int kb = (tile / ntn) * 64, nb = (tile % ntn) * 64;
  int r = threadIdx.x >> 6, c = threadIdx.x & 63;
  #pragma unroll
  for (int p = 0; p < 16; p++)
    t[p * 4 + r][c] = src[(size_t)(kb + p * 4 + r) * W + nb + c];
  __syncthreads();
  #pragma unroll
  for (int p = 0; p < 16; p++)
    dst[(size_t)(nb + p * 4 + r) * HD + kb + c] = f2bf(t[c][p * 4 + r]);
}

// ---- conv: b_batch f32 -> bf16 ----
__global__ __launch_bounds__(256) void k_conv(const float* __restrict__ src,
                                              u16* __restrict__ dst) {
  size_t i = (size_t)blockIdx.x * 256 + threadIdx.x;
  size_t stride = (size_t)gridDim.x * 256;
  const size_t n8 = (size_t)MROWS * HD / 8;
  for (; i < n8; i += stride) {
    float4 a = ((const float4*)src)[2 * i];
    float4 b = ((const float4*)src)[2 * i + 1];
    ushort4 lo, hi;
    lo.x = f2bf(a.x); lo.y = f2bf(a.y); lo.z = f2bf(a.z); lo.w = f2bf(a.w);
    hi.x = f2bf(b.x); hi.y = f2bf(b.y); hi.z = f2bf(b.z); hi.w = f2bf(b.w);
    ((ushort4*)dst)[2 * i] = lo;
    ((ushort4*)dst)[2 * i + 1] = hi;
  }
}

// ---- k_find: two-level histogram (validated R16 — killed the atomic storm) ----
__global__ __launch_bounds__(256) void k_find(const float* __restrict__ is_summ,
    u32* __restrict__ tmp, int* __restrict__ meta) {
  __shared__ int lhist[65];
  __shared__ int lcnt, lbase;
  int tid = threadIdx.x;
  if (tid < 65) lhist[tid] = 0;
  if (tid == 0) lcnt = 0;
  __syncthreads();

  int idx = blockIdx.x * 256 + tid;
  u32 rec = 0; int bk = 0, lofs = 0;
  bool start = false;
  if (idx < MROWS) {
    int b = idx >> 12, t = idx & 4095;
    start = (t == 0) || (is_summ[idx - 1] != 0.0f);
    if (start) {
      int tt = t;
      while (tt < 4095 && is_summ[(b << 12) + tt] == 0.0f) tt++;
      int L = tt - t + 1;
      rec = (u32)idx | ((u32)L << 18);
      bk = L < 64 ? L : 64;
      lofs = atomicAdd(&lcnt, 1);
      atomicAdd(&lhist[bk], 1);
    }
  }
  __syncthreads();
  if (tid == 0) lbase = atomicAdd(&meta[M_NSEG], lcnt);
  if (tid >= 1 && tid <= 64 && lhist[tid] > 0)
    atomicAdd(&meta[M_CNT + tid], lhist[tid]);
  __syncthreads();
  if (start) tmp[lbase + lofs] = rec;
}

__global__ void k_buckets(int* __restrict__ meta) {
  if (threadIdx.x != 0) return;
  int acc = 0;
  for (int L = 64; L >= 1; --L) {
    meta[M_CUR + L] = acc;
    acc += meta[M_CNT + L];
  }
}

// ---- k_scatter: two-level (validated R16) ----
__global__ __launch_bounds__(256) void k_scatter(const u32* __restrict__ tmp,
    u32* __restrict__ sorted, int* __restrict__ meta) {
  __shared__ int lhist[65];
  __shared__ int lbase[65];
  int tid = threadIdx.x;
  if (tid < 65) lhist[tid] = 0;
  __syncthreads();

  int n = meta[M_NSEG];
  int i = blockIdx.x * 256 + tid;
  u32 rec = 0; int bk = 0, lofs = 0;
  bool has = (i < n);
  if (has) {
    rec = tmp[i];
    int L = (int)(rec >> 18);
    bk = L < 64 ? L : 64;
    lofs = atomicAdd(&lhist[bk], 1);
  }
  __syncthreads();
  if (tid >= 1 && tid <= 64 && lhist[tid] > 0)
    lbase[tid] = atomicAdd(&meta[M_CUR + tid], lhist[tid]);
  __syncthreads();
  if (has) sorted[lbase[bk] + lofs] = rec;
}

// ---- MFMA GEMM (validated R10-R16): 128x64 tile, XCD swizzle, bf16 A ----
template<int N>
__global__ __launch_bounds__(256) void k_gemm(const u16* __restrict__ A,
    const u16* __restrict__ BT, const float* __restrict__ bias,
    u16* __restrict__ C) {
  constexpr int NB = N / 64;
  constexpr int NWG = (MROWS / 128) * NB;
  constexpr int CPX = NWG / 8;
  int bid = blockIdx.x;
  int wg = (bid & 7) * CPX + (bid >> 3);
  int mb = wg / NB, nb = wg % NB;
  int wv = threadIdx.x >> 6, lane = threadIdx.x & 63;
  int lr = lane & 15, lk = (lane >> 4) * 8;
  int m0 = mb * 128 + wv * 32;
  int n0 = nb * 64;
  f32x4 acc[2][4] = {};
  #pragma unroll
  for (int kk = 0; kk < 8; kk++) {
    bf16x8 a0 = *(const bf16x8*)(A + (size_t)(m0 + lr) * HD + kk * 32 + lk);
    bf16x8 a1 = *(const bf16x8*)(A + (size_t)(m0 + 16 + lr) * HD + kk * 32 + lk);
    #pragma unroll
    for (int ns = 0; ns < 4; ns++) {
      bf16x8 bv = *(const bf16x8*)(BT + (size_t)(n0 + ns * 16 + lr) * HD + kk * 32 + lk);
      acc[0][ns] = __builtin_amdgcn_mfma_f32_16x16x32_bf16(a0, bv, acc[0][ns], 0, 0, 0);
      acc[1][ns] = __builtin_amdgcn_mfma_f32_16x16x32_bf16(a1, bv, acc[1][ns], 0, 0, 0);
    }
  }
  #pragma unroll
  for (int mi = 0; mi < 2; mi++) {
    int r0 = m0 + mi * 16 + (lane >> 4) * 4;
    #pragma unroll
    for (int ns = 0; ns < 4; ns++) {
      int col = n0 + ns * 16 + lr;
      float bv = bias[col];
      #pragma unroll
      for (int i = 0; i < 4; i++)
        C[(size_t)(r0 + i) * N + col] = f2bf(acc[mi][ns][i] + bv);
    }
  }
}

// ---- scan8: 4 waves/block, 16 segs; h DOUBLE-BUFFERED bf16 in LDS (16 KB).
// No af register cache (A-frags read per-MFMA from LDS) -> low VGPR, no spill.
// bf16 carry numerics == scan6 (validated absmax 0.00390625). 1 barrier/step.
__global__ __launch_bounds__(256, 2) void k_scan8(const u16* __restrict__ gx,
    const u16* __restrict__ WhT, const u16* __restrict__ WoT,
    const float* __restrict__ bh, const float* __restrict__ bo,
    const float* __restrict__ is_summ, float* __restrict__ out,
    float* __restrict__ h_last, const u32* __restrict__ sorted,
    const int* __restrict__ meta) {
  __shared__ u16 h16[2][16 * 256];   // 16 KB total
  int nseg = meta[M_NSEG];
  int tid = threadIdx.x;
  int wv = tid >> 6, lane = tid & 63;
  int lr = lane & 15, g2 = lane >> 4;
  int sbase = blockIdx.x * 16;
  if (sbase >= nseg) return;   // block-uniform

  int gsv[4], Lv[4];
  #pragma unroll
  for (int i = 0; i < 4; i++) {
    int s = sbase + g2 * 4 + i;
    u32 rec = (s < nseg) ? sorted[s] : 0u;
    gsv[i] = (int)(rec & 0x3FFFFu);
    Lv[i]  = (s < nseg) ? (int)(rec >> 18) : 0;
  }
  int lm = max(max(Lv[0], Lv[1]), max(Lv[2], Lv[3]));
  #pragma unroll
  for (int off = 32; off; off >>= 1) lm = max(lm, __shfl_xor(lm, off));
  // lm uniform across waves -> uniform barrier count

  for (int k = 0; k < lm; k++) {
    int cb = k & 1, pb = cb ^ 1;
    if (k == 0) {
      // ---- k=0: h_prev = 0, gh = bh; writes ALL 16 rows of buf 0 ----
      #pragma unroll
      for (int ww = 0; ww < 4; ww++) {
        int w = wv * 4 + ww;
        int col = w * 16 + lr;
        float bhr = bh[col], bhz = bh[col + 256], bhn = bh[col + 512];
        #pragma unroll
        for (int i = 0; i < 4; i++) {
          int row = g2 * 4 + i;
          float hnew = 0.0f;
          if (Lv[i] > 0) {
            int gidx = gsv[i];
            const u16* grow = gx + (size_t)gidx * G3 + col;
            float gr = bf2f(grow[0]), gz = bf2f(grow[256]), gn = bf2f(grow[512]);
            float r = fsig(gr + bhr);
            float z = fsig(gz + bhz);
            float nn = ftanh(gn + r * bhn);
            hnew = (1.0f - z) * nn;
            if (((gidx + 1) & 4095) == 0) {
              float m = 1.0f - is_summ[gidx];
              h_last[(size_t)(gidx >> 12) * HD + col] = m * hnew;
            }
          }
          h16[0][HB(row, col)] = f2bf(hnew);
        }
      }
    } else {
      // ---- phase A: gh = h_{k-1} @ Wh; A-frags from h16[pb] per-MFMA ----
      #pragma unroll
      for (int ww = 0; ww < 4; ww++) {
        int w = wv * 4 + ww;
        f32x4 ar = {0,0,0,0}, az = {0,0,0,0}, an = {0,0,0,0};
        const u16* wr = WhT + (size_t)(w * 16 + lr) * HD + g2 * 8;
        #pragma unroll
        for (int kk = 0; kk < 8; kk++) {
          bf16x8 afk = *(const bf16x8*)&h16[pb][HB(lr, kk * 32 + g2 * 8)];
          bf16x8 b0 = *(const bf16x8*)(wr + kk * 32);
          bf16x8 b1 = *(const bf16x8*)(wr + (size_t)256 * HD + kk * 32);
          bf16x8 b2 = *(const bf16x8*)(wr + (size_t)512 * HD + kk * 32);
          ar = __builtin_amdgcn_mfma_f32_16x16x32_bf16(afk, b0, ar, 0, 0, 0);
          az = __builtin_amdgcn_mfma_f32_16x16x32_bf16(afk, b1, az, 0, 0, 0);
          an = __builtin_amdgcn_mfma_f32_16x16x32_bf16(afk, b2, an, 0, 0, 0);
        }
        int col = w * 16 + lr;
        float bhr = bh[col], bhz = bh[col + 256], bhn = bh[col + 512];
        #pragma unroll
        for (int i = 0; i < 4; i++) {
          if (k < Lv[i]) {
            int row = g2 * 4 + i;
            int gidx = gsv[i] + k;
            const u16* grow = gx + (size_t)gidx * G3 + col;
            float gr = bf2f(grow[0]), gz = bf2f(grow[256]), gn = bf2f(grow[512]);
            float hp = bf2f(h16[pb][HB(row, col)]);
            float r = fsig(gr + ar[i] + bhr);
            float z = fsig(gz + az[i] + bhz);
            float nn = ftanh(gn + r * (an[i] + bhn));
            float hnew = (1.0f - z) * nn + z * hp;
            h16[cb][HB(row, col)] = f2bf(hnew);
            if (((gidx + 1) & 4095) == 0) {
              float m = 1.0f - is_summ[gidx];
              h_last[(size_t)(gidx >> 12) * HD + col] = m * hnew;
            }
          }
        }
      }
    }
    __syncthreads();   // h16[cb] complete (the ONLY barrier per step)
    // ---- phase B: r_out = h_k @ Wo + bo; A-frags from h16[cb] per-MFMA ----
    #pragma unroll
    for (int ww = 0; ww < 4; ww++) {
      int w = wv * 4 + ww;
      f32x4 ao = {0,0,0,0};
      const u16* wr = WoT + (size_t)(w * 16 + lr) * HD + g2 * 8;
      #pragma unroll
      for (int kk = 0; kk < 8; kk++) {
        bf16x8 afk = *(const bf16x8*)&h16[cb][HB(lr, kk * 32 + g2 * 8)];
        bf16x8 bv = *(const bf16x8*)(wr + kk * 32);
        ao = __builtin_amdgcn_mfma_f32_16x16x32_bf16(afk, bv, ao, 0, 0, 0);
      }
      int col = w * 16 + lr;
      float bov = bo[col];
      #pragma unroll
      for (int i = 0; i < 4; i++)
        if (k < Lv[i])
          out[(size_t)(gsv[i] + k) * HD + col] = ao[i] + bov;
    }
    // next phase A writes h16[pb] (untouched by this phase's readers) -> no barrier
  }
}

extern "C" void kernel_launch(void* const* d_in, const int* in_sizes, int n_in,
                              void* d_out, int out_size, void* d_ws, size_t ws_size,
                              hipStream_t stream) {
  const int exp_sizes[8] = {BATCH * TSEQ * HD, BATCH * TSEQ, HD * G3, HD * G3,
                            G3, G3, HD * HD, HD};
  if (n_in != 8) return;
  for (int i = 0; i < 8; i++)
    if (in_sizes[i] != exp_sizes[i]) return;

  const float* b_batch = (const float*)d_in[0];
  const float* is_summ = (const float*)d_in[1];
  const float* Wx = (const float*)d_in[2];
  const float* Wh = (const float*)d_in[3];
  const float* bx = (const float*)d_in[4];
  const float* bh = (const float*)d_in[5];
  const float* Wo = (const float*)d_in[6];
  const float* bo = (const float*)d_in[7];

  float* out = (float*)d_out;
  float* h_last = out + (size_t)MROWS * HD;

  char* ws = (char*)d_ws;
  size_t o = 0;
  u16* gx     = (u16*)(ws + o); o += (size_t)MROWS * G3 * 2;   // 402,653,184
  u16* Abf    = (u16*)(ws + o); o += (size_t)MROWS * HD * 2;   // 134,217,728
  u16* WxT    = (u16*)(ws + o); o += (size_t)G3 * HD * 2;
  u16* WhT    = (u16*)(ws + o); o += (size_t)G3 * HD * 2;
  u16* WoT    = (u16*)(ws + o); o += (size_t)HD * HD * 2;
  int* meta   = (int*)(ws + o); o += 1024;
  u32* tmp    = (u32*)(ws + o); o += (size_t)MROWS * 4;
  u32* sorted = (u32*)(ws + o); o += (size_t)MROWS * 4;
  if (ws_size < o) return;

  k_prep2<<<112, 256, 0, stream>>>(Wx, Wh, Wo, WxT, WhT, WoT, meta);
  k_conv<<<2048, 256, 0, stream>>>(b_batch, Abf);
  k_find<<<MROWS / 256, 256, 0, stream>>>(is_summ, tmp, meta);
  k_buckets<<<1, 64, 0, stream>>>(meta);
  k_scatter<<<MROWS / 256, 256, 0, stream>>>(tmp, sorted, meta);
  k_gemm<G3><<<(MROWS / 128) * (G3 / 64), 256, 0, stream>>>(Abf, WxT, bx, gx);
  k_scan8<<<MROWS / 16, 256, 0, stream>>>(gx, WhT, WoT, bh, bo, is_summ,
                                          out, h_last, sorted, meta);
}